// Round 8
// baseline (96.808 us; speedup 1.0000x reference)
//
#include <hip/hip_runtime.h>
#include <math.h>

// LDDMM variational RHS, Gaussian kernel sigma=0.1, B=1, N=8192, D=3.
// out[0:N*3]     = dmom_i = 100 * (x_i * sum_j W_ij - sum_j W_ij x_j)
// out[N*3:2*N*3] = dcp_i  = sum_j K_ij p_j
// K_ij = exp(-|x_i-x_j|^2/(2 sig^2)), W_ij = K_ij*(p_i.p_j), p=clamp(mom,-1,1)
//
// R14: identical resubmission of R13 (round 7 hit "container failed twice"
// -- broker infra, not a kernel verdict; R13 has no divergent barriers, no
// unbounded loops, 33KB LDS @ 2 blocks/CU -> cannot wedge a device).
//
// R13 rationale: R12 control PASSED (90.3us) -> harness sound. Residual
// (dur-fill) = 46.4/45.6/46.5us across three passes, invariant to ALL
// kernel content (modeled 13-18us) -> remaining suspect: per-dispatch
// overhead (2 kernel dispatches x ~10-15us launch/drain). Test: ONE plain
// dispatch, fully in the proven envelope (plain write-once stores, no
// ws/atomics/memset). Block owns 16 i's; thread (i_local=t>>4, slice
// s=t&15) sums 512 j's; j's staged in 8 chunks of 1024 (32.25KB LDS,
// slice stride 129 float4 spreads the 16 distinct ds_read addrs across
// bank quads); 16 slices of an i sit in 16 consecutive lanes -> shfl_xor
// 1/2/4/8 butterfly; lanes s==0/s==1 write the 6 outputs once each.
// Math/constants R0-verbatim (pkfma builtin).
// Predict: pass; kernel ~13-16us; dur 62-72 if dispatch-gap theory right;
// if ~90 flat with ONE dispatch -> fixed per-replay drain = structural
// floor, declare roofline next round.

#define NPTS   8192
#define N3     (NPTS * 3)
#define THREADS 256
#define IPB    16                    // i's per block
#define NSL    16                    // j-slices per i (lanes t&15)
#define NBLK   (NPTS / IPB)          // 512 blocks (2/CU)
#define CHUNK  1024                  // j's staged per chunk
#define NCHUNK (NPTS / CHUNK)        // 8 chunks
#define CPAIRS (CHUNK / 2)           // 512 j-pairs per chunk
#define SLP    (CPAIRS / NSL)        // 32 pairs per slice per chunk
#define SLSTR  (SLP * 4 + 1)         // 129 float4: slice stride (bank spread)

// exp(-d2/(2*0.1^2)) = exp2(d2 * (-50*log2(e)))
#define COEF    (-72.134752044448170f)
#define M2COEF  (144.269504088896340f)     // -2*COEF
#define UNSC100 (0.69314718055994531f)     // 100 / M2COEF

typedef float v2f __attribute__((ext_vector_type(2)));

__device__ __forceinline__ v2f vsplat(float s) { v2f r; r.x = s; r.y = s; return r; }

__device__ __forceinline__ v2f pkfma(v2f a, v2f b, v2f c) {
#if __has_builtin(__builtin_elementwise_fma)
    return __builtin_elementwise_fma(a, b, c);
#else
    v2f r; r.x = fmaf(a.x, b.x, c.x); r.y = fmaf(a.y, b.y, c.y); return r;
#endif
}

__device__ __forceinline__ float fast_exp2(float x) {
#if __has_builtin(__builtin_amdgcn_exp2f)
    return __builtin_amdgcn_exp2f(x);
#else
    return exp2f(x);
#endif
}

__device__ __forceinline__ float clamp1(float v) {
    return fminf(fmaxf(v, -1.0f), 1.0f);
}

// LDS j-pair entry (4 float4 = 64B), R0/R7-verbatim content:
//  [0] = {M2*x0(j0), M2*x0(j1), M2*x1(j0), M2*x1(j1)}
//  [1] = {M2*x2(j0), M2*x2(j1), cj(j0),    cj(j1)}      cj = COEF*|xj|^2
//  [2] = {p0(j0),    p0(j1),    p1(j0),    p1(j1)}
//  [3] = {p2(j0),    p2(j1),    0,         0}
// Pair P (0..511) of a chunk lives at shj[(P>>5)*SLSTR + (P&31)*4].
__global__ __launch_bounds__(THREADS, 2) void lddmm_all(const float* __restrict__ mom,
                                                        const float* __restrict__ cp,
                                                        float* __restrict__ out) {
    const int t  = (int)threadIdx.x;
    const int ig = t >> 4;               // i_local 0..15
    const int s  = t & 15;               // j-slice 0..15
    const int i  = (int)blockIdx.x * IPB + ig;

    __shared__ float4 shj[NSL * SLSTR];  // 33 KB

    // i-side state: loop-invariant splats.
    const float x0 = cp[i * 3 + 0], x1 = cp[i * 3 + 1], x2 = cp[i * 3 + 2];
    const v2f sx0 = vsplat(x0);
    const v2f sx1 = vsplat(x1);
    const v2f sx2 = vsplat(x2);
    const v2f sci = vsplat(COEF * (x0 * x0 + x1 * x1 + x2 * x2));
    const v2f sp0 = vsplat(clamp1(mom[i * 3 + 0]));
    const v2f sp1 = vsplat(clamp1(mom[i * 3 + 1]));
    const v2f sp2 = vsplat(clamp1(mom[i * 3 + 2]));

    v2f dcp0 = vsplat(0.f), dcp1 = vsplat(0.f), dcp2 = vsplat(0.f);
    v2f wsum = vsplat(0.f);
    v2f wx0 = vsplat(0.f), wx1 = vsplat(0.f), wx2 = vsplat(0.f);

    const int rbase = s * SLSTR;

    for (int c = 0; c < NCHUNK; ++c) {
        __syncthreads();                 // prior chunk's reads complete
        // ---- stage: thread t writes pairs P = 2t, 2t+1 ----
#pragma unroll
        for (int q = 0; q < 2; ++q) {
            const int P  = 2 * t + q;
            const int off = (P >> 5) * SLSTR + (P & 31) * 4;
            const int j0 = c * CHUNK + 2 * P;
            const int j1 = j0 + 1;
            const float xa0 = cp[j0 * 3 + 0], xa1 = cp[j0 * 3 + 1], xa2 = cp[j0 * 3 + 2];
            const float xb0 = cp[j1 * 3 + 0], xb1 = cp[j1 * 3 + 1], xb2 = cp[j1 * 3 + 2];
            shj[off + 0] = make_float4(M2COEF * xa0, M2COEF * xb0,
                                       M2COEF * xa1, M2COEF * xb1);
            shj[off + 1] = make_float4(M2COEF * xa2, M2COEF * xb2,
                                       COEF * (xa0 * xa0 + xa1 * xa1 + xa2 * xa2),
                                       COEF * (xb0 * xb0 + xb1 * xb1 + xb2 * xb2));
            shj[off + 2] = make_float4(clamp1(mom[j0 * 3 + 0]), clamp1(mom[j1 * 3 + 0]),
                                       clamp1(mom[j0 * 3 + 1]), clamp1(mom[j1 * 3 + 1]));
            shj[off + 3] = make_float4(clamp1(mom[j0 * 3 + 2]), clamp1(mom[j1 * 3 + 2]),
                                       0.0f, 0.0f);
        }
        __syncthreads();

        // ---- compute: this thread's 32 pairs (slice s) of the chunk ----
#pragma unroll 8
        for (int p = 0; p < SLP; ++p) {
            const float4 A = shj[rbase + 4 * p + 0];
            const float4 B = shj[rbase + 4 * p + 1];
            const float4 C = shj[rbase + 4 * p + 2];
            const float4 D = shj[rbase + 4 * p + 3];
            v2f xj0p; xj0p.x = A.x; xj0p.y = A.y;
            v2f xj1p; xj1p.x = A.z; xj1p.y = A.w;
            v2f xj2p; xj2p.x = B.x; xj2p.y = B.y;
            v2f cjp;  cjp.x  = B.z; cjp.y  = B.w;
            v2f pj0p; pj0p.x = C.x; pj0p.y = C.y;
            v2f pj1p; pj1p.x = C.z; pj1p.y = C.w;
            v2f pj2p; pj2p.x = D.x; pj2p.y = D.y;

            // arg = ci + cj + xi . (M2*xj) = COEF*d2
            v2f arg = sci + cjp;
            arg = pkfma(sx2, xj2p, arg);
            arg = pkfma(sx1, xj1p, arg);
            arg = pkfma(sx0, xj0p, arg);
            v2f K;
            K.x = fast_exp2(arg.x);
            K.y = fast_exp2(arg.y);
            v2f pd = sp0 * pj0p;
            pd = pkfma(sp1, pj1p, pd);
            pd = pkfma(sp2, pj2p, pd);
            const v2f W = K * pd;
            dcp0 = pkfma(K, pj0p, dcp0);
            dcp1 = pkfma(K, pj1p, dcp1);
            dcp2 = pkfma(K, pj2p, dcp2);
            wsum = wsum + W;
            wx0 = pkfma(W, xj0p, wx0);      // M2COEF-scaled
            wx1 = pkfma(W, xj1p, wx1);
            wx2 = pkfma(W, xj2p, wx2);
        }
    }

    // ---- fold packed halves; butterfly over the 16 slices (lanes s=0..15
    // of this i-group; xor masks <16 stay within the group) ----
    float a0 = dcp0.x + dcp0.y;
    float a1 = dcp1.x + dcp1.y;
    float a2 = dcp2.x + dcp2.y;
    float aw = wsum.x + wsum.y;
    float b0 = wx0.x + wx0.y;
    float b1 = wx1.x + wx1.y;
    float b2 = wx2.x + wx2.y;
#pragma unroll
    for (int m = 1; m <= 8; m <<= 1) {
        a0 += __shfl_xor(a0, m);
        a1 += __shfl_xor(a1, m);
        a2 += __shfl_xor(a2, m);
        aw += __shfl_xor(aw, m);
        b0 += __shfl_xor(b0, m);
        b1 += __shfl_xor(b1, m);
        b2 += __shfl_xor(b2, m);
    }

    // Write-once, plain stores: s==0 writes dcp, s==1 writes dmom.
    if (s == 0) {
        out[N3 + i * 3 + 0] = a0;
        out[N3 + i * 3 + 1] = a1;
        out[N3 + i * 3 + 2] = a2;
    } else if (s == 1) {
        // dmom = 100*xi*wsum - (100/M2COEF)*wxs
        out[i * 3 + 0] = fmaf(100.0f * x0, aw, -UNSC100 * b0);
        out[i * 3 + 1] = fmaf(100.0f * x1, aw, -UNSC100 * b1);
        out[i * 3 + 2] = fmaf(100.0f * x2, aw, -UNSC100 * b2);
    }
}

extern "C" void kernel_launch(void* const* d_in, const int* in_sizes, int n_in,
                              void* d_out, int out_size, void* d_ws, size_t ws_size,
                              hipStream_t stream) {
    const float* mom = (const float*)d_in[0];
    const float* cp  = (const float*)d_in[1];
    float* out = (float*)d_out;

    (void)d_ws; (void)ws_size;  // workspace no longer needed (single kernel)
    hipLaunchKernelGGL(lddmm_all, dim3(NBLK), dim3(THREADS), 0, stream, mom, cp, out);
}

// Round 9
// 88.529 us; speedup vs baseline: 1.0935x; 1.0935x over previous
//
#include <hip/hip_runtime.h>
#include <math.h>

// LDDMM variational RHS, Gaussian kernel sigma=0.1, B=1, N=8192, D=3.
// out[0:N*3]     = dmom_i = 100 * (x_i * sum_j W_ij - sum_j W_ij x_j)
// out[N*3:2*N*3] = dcp_i  = sum_j K_ij p_j
// K_ij = exp(-|x_i-x_j|^2/(2 sig^2)), W_ij = K_ij*(p_i.p_j), p=clamp(mom,-1,1)
//
// R15: R14's counters broke the case: the single-dispatch kernel itself was
// 50us with VALUBusy 34%, LDS_BANK_CONFLICT 9.4M -> the bottleneck is the
// LDS PIPE (2.1M wave ds_read_b128 ~= 41us/CU + 15us conflicts), not VALU.
// Dispatch overhead is small (96.8 = 43.5 fill + 50 kernel + ~3), so R0's
// partial was ~40us all along (masked in top-5 by five ~43us fills); the
// "structural residual" theory is dead. Fix: NO LDS in the hot loop. Three
// plain dispatches (proven envelope): (1) prep writes jdata[j]={M2*x, cj,
// clamp(p), 0} (256KB) into ws; (2) partial = R0 kernel VERBATIM with the
// two LDS reads replaced by two uniform float4 loads of jdata (4KB/block
// working set -> s_load or L1-broadcast; zero LDS); (3) R0 reduce verbatim.
// Predict: partial 40 -> 10-15us (VALUBusy>70%, LDS_Block_Size=0, conflicts
// 0), prep ~2us, reduce ~3.5us, dur ~62-70us. If partial >25us with low
// VALUBusy: loads didn't scalarize -> force via readfirstlane next round.

#define NPTS 8192
#define N3   (NPTS * 3)
#define BI   256
#define IBLK (NPTS / (BI * 2))       // 16 i-blocks (2 i's per thread, packed)
#define JC   64
#define JLEN (NPTS / JC)             // 128 j's per chunk

// exp(-d2/(2*0.1^2)) = exp2(d2 * (-50*log2(e)))
#define COEF    (-72.134752044448170f)
#define M2COEF  (144.269504088896340f)     // -2*COEF
#define UNSC100 (0.69314718055994531f)     // 100 / M2COEF

#define JDF      (NPTS * 8)                              // jdata floats (65536)
#define WS_NEEDED ((size_t)(JDF + JC * NPTS * 8) * sizeof(float))  // ~17.0 MB

typedef float v2f __attribute__((ext_vector_type(2)));

__device__ __forceinline__ v2f vsplat(float s) { v2f r; r.x = s; r.y = s; return r; }

__device__ __forceinline__ v2f pkfma(v2f a, v2f b, v2f c) {
#if __has_builtin(__builtin_elementwise_fma)
    return __builtin_elementwise_fma(a, b, c);
#else
    v2f r; r.x = fmaf(a.x, b.x, c.x); r.y = fmaf(a.y, b.y, c.y); return r;
#endif
}

__device__ __forceinline__ float fast_exp2(float x) {
#if __has_builtin(__builtin_amdgcn_exp2f)
    return __builtin_amdgcn_exp2f(x);
#else
    return exp2f(x);
#endif
}

__device__ __forceinline__ float clamp1(float v) {
    return fminf(fmaxf(v, -1.0f), 1.0f);
}

// ---- prep: jdata[j] = {M2*x0, M2*x1, M2*x2, cj | p0, p1, p2, 0} ----
// (exactly the values R0's LDS staging computed; two plain float4 stores)
__global__ __launch_bounds__(256) void lddmm_prep(const float* __restrict__ mom,
                                                  const float* __restrict__ cp,
                                                  float4* __restrict__ jd4) {
    const int j = (int)blockIdx.x * 256 + (int)threadIdx.x;
    const float x0 = cp[j * 3 + 0], x1 = cp[j * 3 + 1], x2 = cp[j * 3 + 2];
    jd4[2 * j + 0] = make_float4(M2COEF * x0, M2COEF * x1, M2COEF * x2,
                                 COEF * (x0 * x0 + x1 * x1 + x2 * x2));
    jd4[2 * j + 1] = make_float4(clamp1(mom[j * 3 + 0]), clamp1(mom[j * 3 + 1]),
                                 clamp1(mom[j * 3 + 2]), 0.0f);
}

// wpart layout: wpart[((c*NPTS)+i)*8 + k], k=0..3: dcp0,dcp1,dcp2,wsum
//                                         k=4..7: wxs0,wxs1,wxs2,0
// (R0 verbatim except j-data comes from jdata via uniform loads, no LDS)
__global__ __launch_bounds__(BI, 4) void lddmm_partial(const float* __restrict__ mom,
                                                       const float* __restrict__ cp,
                                                       const float4* __restrict__ jd4,
                                                       float* __restrict__ wpart) {
    const int ib = (int)blockIdx.x / JC;
    const int jc = (int)blockIdx.x % JC;
    const int t  = (int)threadIdx.x;
    const int i0 = ib * (BI * 2) + t;     // component .x
    const int i1 = i0 + BI;               // component .y

    // i-side data packed: {i0-value, i1-value}
    v2f xi0, xi1, xi2, ci, pi0, pi1, pi2;
    {
        const float a0 = cp[i0 * 3 + 0], a1 = cp[i0 * 3 + 1], a2 = cp[i0 * 3 + 2];
        const float b0 = cp[i1 * 3 + 0], b1 = cp[i1 * 3 + 1], b2 = cp[i1 * 3 + 2];
        xi0.x = a0; xi0.y = b0;
        xi1.x = a1; xi1.y = b1;
        xi2.x = a2; xi2.y = b2;
        ci.x = COEF * (a0 * a0 + a1 * a1 + a2 * a2);
        ci.y = COEF * (b0 * b0 + b1 * b1 + b2 * b2);
        pi0.x = clamp1(mom[i0 * 3 + 0]); pi0.y = clamp1(mom[i1 * 3 + 0]);
        pi1.x = clamp1(mom[i0 * 3 + 1]); pi1.y = clamp1(mom[i1 * 3 + 1]);
        pi2.x = clamp1(mom[i0 * 3 + 2]); pi2.y = clamp1(mom[i1 * 3 + 2]);
    }

    v2f dcp0 = vsplat(0.f), dcp1 = vsplat(0.f), dcp2 = vsplat(0.f);
    v2f wsum = vsplat(0.f);
    v2f wx0 = vsplat(0.f), wx1 = vsplat(0.f), wx2 = vsplat(0.f);

    const int jbase = jc * JLEN;

#pragma unroll 8
    for (int jj = 0; jj < JLEN; ++jj) {
        // wave-uniform index -> scalar load / single-line L1 broadcast
        const float4 xj = jd4[(jbase + jj) * 2 + 0];
        const float4 pj = jd4[(jbase + jj) * 2 + 1];

        // arg = ci + cj + dot(xi, M2COEF*xj) = COEF*d2  (1 pk_add + 3 pk_fma)
        v2f arg = ci + vsplat(xj.w);
        arg = pkfma(xi2, vsplat(xj.z), arg);
        arg = pkfma(xi1, vsplat(xj.y), arg);
        arg = pkfma(xi0, vsplat(xj.x), arg);
        v2f K;                               // 2 trans
        K.x = fast_exp2(arg.x);
        K.y = fast_exp2(arg.y);
        v2f pd = pi0 * vsplat(pj.x);         // 1 pk_mul + 2 pk_fma
        pd = pkfma(pi1, vsplat(pj.y), pd);
        pd = pkfma(pi2, vsplat(pj.z), pd);
        const v2f W = K * pd;                // 1 pk_mul
        dcp0 = pkfma(K, vsplat(pj.x), dcp0); // 3 pk_fma
        dcp1 = pkfma(K, vsplat(pj.y), dcp1);
        dcp2 = pkfma(K, vsplat(pj.z), dcp2);
        wsum = wsum + W;                     // 1 pk_add
        wx0 = pkfma(W, vsplat(xj.x), wx0);   // 3 pk_fma (M2COEF-scaled)
        wx1 = pkfma(W, vsplat(xj.y), wx1);
        wx2 = pkfma(W, vsplat(xj.z), wx2);
    }

    float4* oa = (float4*)(wpart + ((size_t)(jc * NPTS) + i0) * 8);
    oa[0] = make_float4(dcp0.x, dcp1.x, dcp2.x, wsum.x);
    oa[1] = make_float4(wx0.x, wx1.x, wx2.x, 0.0f);
    float4* ob = (float4*)(wpart + ((size_t)(jc * NPTS) + i1) * 8);
    ob[0] = make_float4(dcp0.y, dcp1.y, dcp2.y, wsum.y);
    ob[1] = make_float4(wx0.y, wx1.y, wx2.y, 0.0f);
}

// 4 threads per i: sub=(cpart,half). Each sums JC/2 chunks of one float4,
// xor-2 combines chunk halves, xor-1 hands wsum from half0 to half1.
// dmom = 100*xi*wsum - (100/M2COEF)*wxs.  (R0 verbatim)
__global__ __launch_bounds__(256) void lddmm_reduce(const float* __restrict__ wpart,
                                                    const float* __restrict__ cp,
                                                    float* __restrict__ out) {
    const int tid   = (int)blockIdx.x * 256 + (int)threadIdx.x;
    const int i     = tid >> 2;
    const int sub   = tid & 3;
    const int half  = sub & 1;
    const int cpart = sub >> 1;

    float4 acc = make_float4(0.f, 0.f, 0.f, 0.f);
    const int c0 = cpart * (JC / 2);
#pragma unroll 4
    for (int c = c0; c < c0 + JC / 2; ++c) {
        const float4 v = ((const float4*)(wpart + ((size_t)(c * NPTS) + i) * 8))[half];
        acc.x += v.x; acc.y += v.y; acc.z += v.z; acc.w += v.w;
    }
    acc.x += __shfl_xor(acc.x, 2);
    acc.y += __shfl_xor(acc.y, 2);
    acc.z += __shfl_xor(acc.z, 2);
    acc.w += __shfl_xor(acc.w, 2);
    const float wsum = __shfl_xor(acc.w, 1);
    if (sub == 0) {
        out[N3 + i * 3 + 0] = acc.x;
        out[N3 + i * 3 + 1] = acc.y;
        out[N3 + i * 3 + 2] = acc.z;
    } else if (sub == 1) {
        const float xi0 = cp[i * 3 + 0];
        const float xi1 = cp[i * 3 + 1];
        const float xi2 = cp[i * 3 + 2];
        out[i * 3 + 0] = fmaf(100.0f * xi0, wsum, -UNSC100 * acc.x);
        out[i * 3 + 1] = fmaf(100.0f * xi1, wsum, -UNSC100 * acc.y);
        out[i * 3 + 2] = fmaf(100.0f * xi2, wsum, -UNSC100 * acc.z);
    }
}

// ---- fallback (atomics into d_out) if ws_size < WS_NEEDED; never runs in
// this harness (ws is 268MB) -- dead code kept from the passing R0. ----
#define FJC   32
#define FJLEN (NPTS / FJC)
__global__ __launch_bounds__(BI) void lddmm_pairs_atomic(const float* __restrict__ mom,
                                                         const float* __restrict__ cp,
                                                         float* __restrict__ out) {
    const int ib = (int)blockIdx.x / FJC;
    const int jc = (int)blockIdx.x % FJC;
    const int t  = (int)threadIdx.x;
    const int i  = ib * BI + t;

    const float xi0 = cp[i * 3 + 0], xi1 = cp[i * 3 + 1], xi2 = cp[i * 3 + 2];
    const float pi0 = clamp1(mom[i * 3 + 0]), pi1 = clamp1(mom[i * 3 + 1]),
                pi2 = clamp1(mom[i * 3 + 2]);

    __shared__ float4 shx[FJLEN];
    __shared__ float4 shp[FJLEN];
    {
        const int j = jc * FJLEN + t;
        shx[t] = make_float4(cp[j * 3 + 0], cp[j * 3 + 1], cp[j * 3 + 2], 0.0f);
        shp[t] = make_float4(clamp1(mom[j * 3 + 0]), clamp1(mom[j * 3 + 1]),
                             clamp1(mom[j * 3 + 2]), 0.0f);
    }
    __syncthreads();

    float dcp0 = 0.f, dcp1 = 0.f, dcp2 = 0.f, wsum = 0.f, wx0 = 0.f, wx1 = 0.f, wx2 = 0.f;
#pragma unroll 4
    for (int jj = 0; jj < FJLEN; ++jj) {
        const float4 xj = shx[jj];
        const float4 pj = shp[jj];
        const float dx0 = xi0 - xj.x, dx1 = xi1 - xj.y, dx2 = xi2 - xj.z;
        const float d2  = dx0 * dx0 + dx1 * dx1 + dx2 * dx2;
        const float K   = fast_exp2(d2 * COEF);
        const float pd  = pi0 * pj.x + pi1 * pj.y + pi2 * pj.z;
        const float W   = K * pd;
        dcp0 += K * pj.x; dcp1 += K * pj.y; dcp2 += K * pj.z;
        wsum += W;
        wx0 += W * xj.x; wx1 += W * xj.y; wx2 += W * xj.z;
    }
    atomicAdd(&out[i * 3 + 0], 100.0f * (xi0 * wsum - wx0));
    atomicAdd(&out[i * 3 + 1], 100.0f * (xi1 * wsum - wx1));
    atomicAdd(&out[i * 3 + 2], 100.0f * (xi2 * wsum - wx2));
    atomicAdd(&out[N3 + i * 3 + 0], dcp0);
    atomicAdd(&out[N3 + i * 3 + 1], dcp1);
    atomicAdd(&out[N3 + i * 3 + 2], dcp2);
}

extern "C" void kernel_launch(void* const* d_in, const int* in_sizes, int n_in,
                              void* d_out, int out_size, void* d_ws, size_t ws_size,
                              hipStream_t stream) {
    const float* mom = (const float*)d_in[0];
    const float* cp  = (const float*)d_in[1];
    float* out = (float*)d_out;

    if (ws_size >= WS_NEEDED) {
        float* ws = (float*)d_ws;
        float4* jd4   = (float4*)ws;           // 256 KB
        float*  wpart = ws + JDF;              // 16.78 MB
        hipLaunchKernelGGL(lddmm_prep, dim3(NPTS / 256), dim3(256), 0, stream,
                           mom, cp, jd4);
        hipLaunchKernelGGL(lddmm_partial, dim3(IBLK * JC), dim3(BI), 0, stream,
                           mom, cp, jd4, wpart);
        hipLaunchKernelGGL(lddmm_reduce, dim3(NPTS * 4 / 256), dim3(256), 0, stream,
                           wpart, cp, out);
    } else {
        hipMemsetAsync(out, 0, (size_t)out_size * sizeof(float), stream);
        hipLaunchKernelGGL(lddmm_pairs_atomic, dim3((NPTS / BI) * FJC), dim3(BI), 0,
                           stream, mom, cp, out);
    }
}